// Round 4
// baseline (175.668 us; speedup 1.0000x reference)
//
#include <hip/hip_runtime.h>
#include <math.h>

#define Bn 32
#define Pn 32768
#define On 32

// d_ws layout:
// [0,     8192)   u64   bpm[Bn*On]    packed (iou_bits<<32 | (Pn-1-p))
// [8192,  8320)   int   num_pos[Bn]
// [8320,  8324)   float loss_l_total
// [8324,  8328)   float ce_total
// [8328,  8332)   int   np_total
// [16384, 16384+Bn*Pn)          uchar pack[Bn*Pn]  (bx | flag<<5)
// [16384+Bn*Pn, +4*Bn*Pn)       float ce_mine[Bn*Pn]

// ---------- Phase 1: single IoU pass; per-p AND per-o argmax ----------
// grid (Pn/1024, Bn), 256 thr, 4 consecutive priors/thread in registers.
__global__ __launch_bounds__(256) void phase1(const float4* __restrict__ priors,
                                              const float* __restrict__ targets,
                                              unsigned long long* __restrict__ bpm,
                                              uchar4* __restrict__ pack) {
    int b = blockIdx.y;
    int base = blockIdx.x * 1024;
    int tid = threadIdx.x;
    int lane = tid & 63, wv = tid >> 6;

    __shared__ float4 tb[On];
    __shared__ float  ta[On];
    __shared__ unsigned long long wred[On][4];

    if (tid < On) {
        const float* t = targets + ((size_t)b * On + tid) * 5;
        float x1 = t[0], y1 = t[1], x2 = t[2], y2 = t[3];
        tb[tid] = make_float4(x1, y1, x2, y2);
        ta[tid] = (x2 - x1) * (y2 - y1);
    }
    __syncthreads();

    int p0 = base + tid * 4;
    float px1[4], py1[4], px2[4], py2[4], ab[4];
#pragma unroll
    for (int j = 0; j < 4; j++) {
        float4 pr = priors[p0 + j];
        px1[j] = pr.x - pr.z * 0.5f; py1[j] = pr.y - pr.w * 0.5f;
        px2[j] = pr.x + pr.z * 0.5f; py2[j] = pr.y + pr.w * 0.5f;
        ab[j]  = (px2[j] - px1[j]) * (py2[j] - py1[j]);
    }

    float bI[4] = {0.f, 0.f, 0.f, 0.f};
    float bU[4] = {1.f, 1.f, 1.f, 1.f};
    int   bx[4] = {0, 0, 0, 0};

    for (int o = 0; o < On; o++) {
        float4 tt = tb[o];
        float  a  = ta[o];
        float I[4], U[4];
#pragma unroll
        for (int j = 0; j < 4; j++) {
            float ix1 = fmaxf(tt.x, px1[j]), iy1 = fmaxf(tt.y, py1[j]);
            float ix2 = fminf(tt.z, px2[j]), iy2 = fminf(tt.w, py2[j]);
            float iw = fmaxf(ix2 - ix1, 0.f), ih = fmaxf(iy2 - iy1, 0.f);
            I[j] = iw * ih;
            U[j] = a + ab[j] - I[j];
            // per-prior argmax over truths (strict >: first o wins ties)
            if (I[j] * bU[j] > bI[j] * U[j]) { bI[j] = I[j]; bU[j] = U[j]; bx[j] = o; }
        }
        // per-truth: thread-local best over 4 consecutive priors (ascending p, first wins)
        float cI = I[0], cU = U[0]; int cp = p0;
#pragma unroll
        for (int j = 1; j < 4; j++)
            if (I[j] * cU > cI * U[j]) { cI = I[j]; cU = U[j]; cp = p0 + j; }
        float iou = cI / cU;     // f32 quotient so cross-thread ties match the ref
        unsigned long long key = ((unsigned long long)__float_as_uint(iou) << 32)
                               | (unsigned)(Pn - 1 - cp);
#pragma unroll
        for (int off = 32; off > 0; off >>= 1) {
            unsigned long long ok = __shfl_down(key, off, 64);
            if (ok > key) key = ok;
        }
        if (lane == 0) wred[o][wv] = key;
    }
    __syncthreads();
    if (tid < On) {
        unsigned long long kk = wred[tid][0];
#pragma unroll
        for (int w = 1; w < 4; w++) if (wred[tid][w] > kk) kk = wred[tid][w];
        atomicMax(&bpm[b * On + tid], kk);
    }

    uchar4 pk;
    pk.x = (unsigned char)(bx[0] | ((bI[0] >= 0.5f * bU[0]) ? 32 : 0));
    pk.y = (unsigned char)(bx[1] | ((bI[1] >= 0.5f * bU[1]) ? 32 : 0));
    pk.z = (unsigned char)(bx[2] | ((bI[2] >= 0.5f * bU[2]) ? 32 : 0));
    pk.w = (unsigned char)(bx[3] | ((bI[3] >= 0.5f * bU[3]) ? 32 : 0));
    pack[(size_t)b * (Pn / 4) + blockIdx.x * 256 + tid] = pk;
}

// ---------- Phase 2: epilogue — forced override, losses, ce_mine ----------
// grid (Pn/1024, Bn), 256 thr, 4 consecutive priors/thread.
__global__ __launch_bounds__(256) void phase2(const float* __restrict__ loc,
                                              const float4* __restrict__ conf4,
                                              const float4* __restrict__ priors,
                                              const float* __restrict__ targets,
                                              const unsigned long long* __restrict__ bpm,
                                              const uchar4* __restrict__ pack,
                                              float* __restrict__ ce_mine,
                                              int* __restrict__ num_pos,
                                              float* __restrict__ loss_l_t,
                                              float* __restrict__ ce_t,
                                              int* __restrict__ np_tot) {
    int b = blockIdx.y;
    int base = blockIdx.x * 1024;
    int tid = threadIdx.x;

    __shared__ float4 tb[On];
    __shared__ float  lb[On];
    __shared__ int    forced[1024];
    __shared__ float  sred[12];

    forced[tid] = -1; forced[tid + 256] = -1; forced[tid + 512] = -1; forced[tid + 768] = -1;
    int sp = -1;
    if (tid < On) {
        const float* t = targets + ((size_t)b * On + tid) * 5;
        tb[tid] = make_float4(t[0], t[1], t[2], t[3]);
        lb[tid] = t[4];
        sp = Pn - 1 - (int)(bpm[b * On + tid] & 0xFFFFFFFFull);
    }
    __syncthreads();
    if (tid < On && sp >= base && sp < base + 1024)
        atomicMax(&forced[sp - base], tid);    // duplicate bpi: max o == numpy last write
    __syncthreads();

    int p0 = base + tid * 4;
    uchar4 pk = pack[(size_t)b * (Pn / 4) + blockIdx.x * 256 + tid];
    size_t cb = ((size_t)b * Pn + p0) >> 1;
    float4 cA = conf4[cb], cB = conf4[cb + 1];

    unsigned char pkb[4] = {pk.x, pk.y, pk.z, pk.w};
    float c0a[4] = {cA.x, cA.z, cB.x, cB.z};
    float c1a[4] = {cA.y, cA.w, cB.y, cB.w};
    float cem[4];
    float ll_s = 0.f, pce_s = 0.f, cnt_s = 0.f;

#pragma unroll
    for (int j = 0; j < 4; j++) {
        int fo = forced[tid * 4 + j];
        int bidx = (fo >= 0) ? fo : (pkb[j] & 31);
        int cf = ((fo >= 0) || (pkb[j] & 32)) ? (int)lb[bidx] : 0;
        bool pos = cf > 0;
        if (pos) {
            float4 tt = tb[bidx];
            float4 pr = priors[p0 + j];
            float g0 = ((tt.x + tt.z) * 0.5f - pr.x) / (0.1f * pr.z);
            float g1 = ((tt.y + tt.w) * 0.5f - pr.y) / (0.1f * pr.w);
            float g2 = __logf((tt.z - tt.x) / pr.z) * 5.0f;
            float g3 = __logf((tt.w - tt.y) / pr.w) * 5.0f;
            const float* lp = loc + ((size_t)b * Pn + p0 + j) * 3;
            float q0 = lp[0], q1 = lp[1], q2 = lp[2];
            float dd[4] = { q0 - g0, q1 - g1, q2 - g2, q2 - g3 };
#pragma unroll
            for (int i = 0; i < 4; i++) {
                float ad = fabsf(dd[i]);
                ll_s += (ad < 1.f) ? 0.5f * dd[i] * dd[i] : (ad - 0.5f);
            }
            cnt_s += 1.f;
        }
        float m = fmaxf(c0a[j], c1a[j]);
        float lse = m + __logf(__expf(c0a[j] - m) + __expf(c1a[j] - m));
        float ce = lse - (cf ? c1a[j] : c0a[j]);
        if (pos) { pce_s += ce; ce = 0.f; }
        cem[j] = fmaxf(ce, 0.f);
    }
    ((float4*)ce_mine)[((size_t)b * Pn + p0) >> 2] = make_float4(cem[0], cem[1], cem[2], cem[3]);

#pragma unroll
    for (int off = 32; off > 0; off >>= 1) {
        ll_s  += __shfl_down(ll_s,  off, 64);
        pce_s += __shfl_down(pce_s, off, 64);
        cnt_s += __shfl_down(cnt_s, off, 64);
    }
    int lane = tid & 63, wv = tid >> 6;
    if (lane == 0) { sred[wv*3] = ll_s; sred[wv*3+1] = pce_s; sred[wv*3+2] = cnt_s; }
    __syncthreads();
    if (tid == 0) {
        float llr = 0, pcer = 0, cntr = 0;
        for (int w = 0; w < 4; w++) { llr += sred[w*3]; pcer += sred[w*3+1]; cntr += sred[w*3+2]; }
        if (llr != 0.f)  atomicAdd(loss_l_t, llr);
        if (pcer != 0.f) atomicAdd(ce_t, pcer);
        int c = (int)cntr;
        if (c) { atomicAdd(&num_pos[b], c); atomicAdd(np_tot, c); }
    }
}

// ---------- Phase 3: exact top-k sum, register bisection, 1 barrier/round ----------
__global__ __launch_bounds__(1024) void topk(const float* __restrict__ ce_mine,
                                             const int* __restrict__ num_pos,
                                             float* __restrict__ ce_t) {
    int b = blockIdx.x, tid = threadIdx.x;
    const float4* v4 = (const float4*)(ce_mine + (size_t)b * Pn);
    float4 r[8];
#pragma unroll
    for (int i = 0; i < 8; i++) r[i] = v4[i * 1024 + tid];

    int k = 3 * num_pos[b];
    if (k > Pn - 1) k = Pn - 1;
    if (k <= 0) return;

    __shared__ int   scnt[34];
    __shared__ float ssum[16];
    __shared__ int   sct[16];
    for (int i = tid; i < 34; i += 1024) scnt[i] = 0;
    __syncthreads();

    // invariant: count(>lo) >= k, count(>hi) < k
    unsigned lo = 0u, hi = 0x7F800000u;
    int round = 0;
    while (hi - lo > 1u && round < 32) {
        unsigned mid = lo + ((hi - lo) >> 1);
        float mf = __uint_as_float(mid);
        int c = 0;
#pragma unroll
        for (int i = 0; i < 8; i++)
            c += (r[i].x > mf) + (r[i].y > mf) + (r[i].z > mf) + (r[i].w > mf);
#pragma unroll
        for (int off = 32; off > 0; off >>= 1) c += __shfl_down(c, off, 64);
        if ((tid & 63) == 0) atomicAdd(&scnt[round], c);
        __syncthreads();
        int tot = scnt[round];
        round++;
        if (tot == k) { hi = mid; break; }   // exactly k exceed mid -> exact top-k cut
        if (tot >= k) lo = mid; else hi = mid;
    }

    float tv = __uint_as_float(hi);
    float s = 0.f; int c = 0;
#pragma unroll
    for (int i = 0; i < 8; i++) {
        if (r[i].x > tv) { s += r[i].x; c++; }
        if (r[i].y > tv) { s += r[i].y; c++; }
        if (r[i].z > tv) { s += r[i].z; c++; }
        if (r[i].w > tv) { s += r[i].w; c++; }
    }
#pragma unroll
    for (int off = 32; off > 0; off >>= 1) {
        s += __shfl_down(s, off, 64);
        c += __shfl_down(c, off, 64);
    }
    if ((tid & 63) == 0) { ssum[tid >> 6] = s; sct[tid >> 6] = c; }
    __syncthreads();
    if (tid == 0) {
        float st = 0.f; int ct = 0;
        for (int w = 0; w < 16; w++) { st += ssum[w]; ct += sct[w]; }
        atomicAdd(ce_t, st + (float)(k - ct) * tv);   // ties at tau, tie-agnostic exact
    }
}

// ---------------- finalize ----------------
__global__ void finalize(const float* __restrict__ loss_l_t,
                         const float* __restrict__ ce_t,
                         const int* __restrict__ np_tot,
                         float* __restrict__ out) {
    float N = (float)(*np_tot);
    out[0] = *loss_l_t / N;
    out[1] = *ce_t / N;
}

extern "C" void kernel_launch(void* const* d_in, const int* in_sizes, int n_in,
                              void* d_out, int out_size, void* d_ws, size_t ws_size,
                              hipStream_t stream) {
    const float* loc     = (const float*)d_in[0];  // (B,P,3)
    const float* conf    = (const float*)d_in[1];  // (B,P,2)
    const float* priors  = (const float*)d_in[2];  // (P,4)
    const float* targets = (const float*)d_in[3];  // (B,O,5)
    float* out = (float*)d_out;

    char* ws = (char*)d_ws;
    unsigned long long* bpm = (unsigned long long*)ws;
    int*   num_pos  = (int*)(ws + 8192);
    float* loss_l_t = (float*)(ws + 8320);
    float* ce_t     = (float*)(ws + 8324);
    int*   np_tot   = (int*)(ws + 8328);
    uchar4* pack    = (uchar4*)(ws + 16384);
    float* ce_mine  = (float*)(ws + 16384 + (size_t)Bn * Pn);

    hipMemsetAsync(ws, 0, 16384, stream);

    hipLaunchKernelGGL(phase1, dim3(Pn / 1024, Bn), dim3(256), 0, stream,
                       (const float4*)priors, targets, bpm, pack);
    hipLaunchKernelGGL(phase2, dim3(Pn / 1024, Bn), dim3(256), 0, stream,
                       loc, (const float4*)conf, (const float4*)priors, targets, bpm, pack,
                       ce_mine, num_pos, loss_l_t, ce_t, np_tot);
    hipLaunchKernelGGL(topk, dim3(Bn), dim3(1024), 0, stream, ce_mine, num_pos, ce_t);
    hipLaunchKernelGGL(finalize, dim3(1), dim3(1), 0, stream, loss_l_t, ce_t, np_tot, out);
}